// Round 3
// baseline (798.772 us; speedup 1.0000x reference)
//
#include <hip/hip_runtime.h>

typedef unsigned short u16;
typedef unsigned int   u32;
typedef __attribute__((ext_vector_type(8))) short short8;
typedef __attribute__((ext_vector_type(4))) float f4;

#define BT 8
#define TX 30
#define TY 10

__device__ __forceinline__ float bf2f_u16(u16 h){ u32 i=((u32)h)<<16; float f; __builtin_memcpy(&f,&i,4); return f; }
__device__ __forceinline__ float lo2f(u32 p){ u32 i=p<<16; float f; __builtin_memcpy(&f,&i,4); return f; }
__device__ __forceinline__ float hi2f(u32 p){ u32 i=p&0xffff0000u; float f; __builtin_memcpy(&f,&i,4); return f; }
__device__ __forceinline__ u16 f2bf(float f){ u32 x; __builtin_memcpy(&x,&f,4); u32 r=(x+0x7fffu+((x>>16)&1u))>>16; return (u16)r; }

#if __has_builtin(__builtin_amdgcn_rcpf)
__device__ __forceinline__ float frcp(float x){ return __builtin_amdgcn_rcpf(x); }
#else
__device__ __forceinline__ float frcp(float x){ return 1.0f/x; }
#endif
// fast activations: single v_exp + v_rcp (no fp32 div sequence)
__device__ __forceinline__ float sigm(float x){ return frcp(1.0f+__expf(-x)); }
__device__ __forceinline__ float tanh_(float x){ x=fminf(fmaxf(x,-15.0f),15.0f); float e=__expf(2.0f*x); return 1.0f - 2.0f*frcp(e+1.0f); }

__device__ __forceinline__ f4 mfma16(short8 a, short8 b, f4 c){
    return __builtin_amdgcn_mfma_f32_16x16x32_bf16(a, b, c, 0, 0, 0);
}

// async global->LDS, 16B per lane; LDS dest = wave-uniform base + lane*16
__device__ __forceinline__ void gload_lds16(const float* g, float* l){
    __builtin_amdgcn_global_load_lds((const __attribute__((address_space(1))) void*)g,
                                     (__attribute__((address_space(3))) void*)l, 16, 0, 0);
}

union S8u { short8 s; u32 u[4]; };

// pack hi-halves of two fp32 into one u32 (truncated bf16 pair), residual -> lo pair
__device__ __forceinline__ void cvt_pair(float a0, float a1, u32& hp, u32& lp){
    u32 u0, u1; __builtin_memcpy(&u0,&a0,4); __builtin_memcpy(&u1,&a1,4);
    hp = __builtin_amdgcn_perm(u1, u0, 0x07060302u);          // [hi16(a1) : hi16(a0)]
    float r0 = a0 - hi2f(u0);
    float r1 = a1 - hi2f(u1);
    u32 v0, v1; __builtin_memcpy(&v0,&r0,4); __builtin_memcpy(&v1,&r1,4);
    lp = __builtin_amdgcn_perm(v1, v0, 0x07060302u);
}

struct SDec {
    float aW1[BT][TX][10];      // b1 + a @ W1[:, :64].T  (ty-invariant), computed via MFMA
    u16 sh[BT][72], sl[BT][72]; // s hi/lo bf16, A-frag rows 0-7 (rows 8-15 -> zr2)
    u16 ctxh[BT][72], ctxl[BT][72];
    u16 zr2[72];                // always-zero row (decoder A-frag filler for mL>=8)
    float sW1[BT][12];
    float en[BT][32];
    float w2b[12]; float b2s;
};
struct SEnc {
    u16 h[2][2][2][BT][40];     // [parity][dir][hi/lo][m][k], K=32 pad 40   (5120 B)
    u16 zr[40];                 // always-zero row (A-frag filler)           (80 B)
    // x pair stage: [pair parity][dir][step][row][128 f32], 16B blocks kb stored
    // at physical pkb = (kb&24)|((kb&7)^row)  (both-sides swizzle, bank spread)
    float xs[2][2][2][BT][128]; // 16384 B  (written by global_load_lds, linear dest)
};
union UU { SEnc e; SDec d; };
struct Smem {
    u16 a[BT][TX][64];          // encoder outputs bf16, row = 128 B (16B-aligned)
    UU u;
};
// LDS: 30720 + 21584 = 52304 B -> 3 blocks/CU (3*52304 = 156912 <= 163840).
// Register diet: x prefetch moved regs->LDS (-64 VGPR) so __launch_bounds__(256,3)
// fits WITHOUT the round-1 spill storm (watch WRITE_SIZE ~= 41 MB as the check).

__global__ __launch_bounds__(256, 3) void fused_kernel(
    const float* __restrict__ X,
    const float* __restrict__ Wihf, const float* __restrict__ Whhf, const float* __restrict__ bfv,
    const float* __restrict__ Wihr, const float* __restrict__ Whhr, const float* __restrict__ brv,
    const float* __restrict__ W1, const float* __restrict__ b1, const float* __restrict__ W2, const float* __restrict__ b2,
    const float* __restrict__ Wihp, const float* __restrict__ Whhp, const float* __restrict__ bp,
    const float* __restrict__ Wo, const float* __restrict__ bo,
    float* __restrict__ out)
{
    __shared__ __align__(16) Smem sm;
    const int tid = threadIdx.x;
    const int b0  = blockIdx.x * BT;

    const int lane = tid & 63;
    const int wv   = tid >> 6;     // wave 0..3
    const int mL   = lane & 15;    // frag non-K index
    const int qL   = lane >> 4;    // quad
    const int k0q  = qL * 8;
    const int ed   = wv >> 1;      // encoder dir
    const int ub   = (wv & 1) * 16;// encoder unit base within NA=32
    const int row8 = mL & 7;       // batch row within frag
    const int sstep= mL >> 3;      // 0: step t rows, 1: step t+1 rows

    // stage x pair (steps t, t+1) for this dir into parity buffer (t>>1)&1.
    // 8 calls of 64 lanes x 16B cover 2*8*128 f32; the dir's two waves split 4/4.
    auto stage = [&](int t){
        if (t >= TX) return;
        float* xb = &sm.u.e.xs[(t>>1)&1][ed][0][0][0];
        const int cbase = (wv & 1) * 4;
        #pragma unroll
        for (int c = 0; c < 4; c++){
            const int P   = (cbase + c)*64 + lane;      // physical 16B-block index
            const int st  = P >> 8;                     // step in pair
            const int rw  = (P >> 5) & 7;               // batch row
            const int pkb = P & 31;
            const int kb  = (pkb & 24) | ((pkb & 7) ^ rw);  // logical k-block (inverse swz)
            const int ts  = ed ? (TX-1-(t+st)) : (t+st);
            const float* src = X + ((long)(b0 + rw))*TX*128 + ts*128 + kb*4;
            gload_lds16(src, xb + (cbase + c)*256);
        }
    };

    {   // zero h bufs + zr (5200 B); xs needs no init (fully staged before read)
        u32* p = (u32*)&sm.u.e;
        for (int i = tid; i < 1300; i += 256) p[i] = 0u;
    }
    stage(0);                       // first pair; arrival guaranteed by barrier drain
    __syncthreads();

    // ===================== encoder =====================
    const float* Wih = ed ? Wihr : Wihf;
    const float* Whh = ed ? Whhr : Whhf;
    const float* bv  = ed ? brv  : bfv;

    short8 Bih[4][4]; short8 Bhh[4]; float bias4[4];
    #pragma unroll
    for (int gt = 0; gt < 4; gt++){
        const int n = gt*32 + ub + mL;                  // gate row (i,f,g,o chunks of 32)
        #pragma unroll
        for (int kt = 0; kt < 4; kt++){
            const float* p = Wih + n*128 + kt*32 + k0q;
            short8 s;
            #pragma unroll
            for (int j = 0; j < 8; j++) s[j] = (short)f2bf(p[j]);
            Bih[gt][kt] = s;
        }
        {
            const float* p = Whh + n*32 + k0q;
            short8 s;
            #pragma unroll
            for (int j = 0; j < 8; j++) s[j] = (short)f2bf(p[j]);
            Bhh[gt] = s;
        }
        bias4[gt] = bv[n];
    }

    float cst[4] = {0.f,0.f,0.f,0.f};  // c-state: lives in qL<2 lanes before even steps, swaps via shfl_xor 32

    // pair processor: steps (t, t+1); M rows 0-7 = step t, 8-15 = step t+1
    auto epair = [&](int t){
        stage(t + 2);                                    // prefetch next pair into other parity
        const int rb = (t+1) & 1, wb = t & 1;            // h_{t-1} in buf rb; h_t -> buf wb; h_{t+1} -> buf rb

        const float* xb = &sm.u.e.xs[(t>>1)&1][ed][0][0][0];
        const int rbase = (sstep*8 + row8)*32;           // this lane's row-block base

        f4 acc[4];
        #pragma unroll
        for (int gt = 0; gt < 4; gt++) acc[gt] = (f4){bias4[gt],bias4[gt],bias4[gt],bias4[gt]};

        #pragma unroll
        for (int kt = 0; kt < 4; kt++){                  // x-GEMM, both steps at once
            const int pA = kt*8 + ((qL*2)     ^ row8);   // swizzled 16B slots
            const int pB = kt*8 + ((qL*2 + 1) ^ row8);
            const f4 v0 = *(const f4*)(xb + (rbase + pA)*4);
            const f4 v1 = *(const f4*)(xb + (rbase + pB)*4);
            S8u xh, xl;
            cvt_pair(v0[0], v0[1], xh.u[0], xl.u[0]);
            cvt_pair(v0[2], v0[3], xh.u[1], xl.u[1]);
            cvt_pair(v1[0], v1[1], xh.u[2], xl.u[2]);
            cvt_pair(v1[2], v1[3], xh.u[3], xl.u[3]);
            #pragma unroll
            for (int gt = 0; gt < 4; gt++){
                acc[gt] = mfma16(xh.s, Bih[gt][kt], acc[gt]);
                acc[gt] = mfma16(xl.s, Bih[gt][kt], acc[gt]);
            }
        }
        {   // h-MFMA step t: A rows 0-7 = h_{t-1}, rows 8-15 = 0
            const short8 Ahh = *(const short8*)((mL < 8) ? &sm.u.e.h[rb][ed][0][mL][k0q] : &sm.u.e.zr[k0q]);
            const short8 Ahl = *(const short8*)((mL < 8) ? &sm.u.e.h[rb][ed][1][mL][k0q] : &sm.u.e.zr[k0q]);
            #pragma unroll
            for (int gt = 0; gt < 4; gt++){
                acc[gt] = mfma16(Ahh, Bhh[gt], acc[gt]);
                acc[gt] = mfma16(Ahl, Bhh[gt], acc[gt]);
            }
        }
        if (qL < 2){                                     // cell update step t (rows 0-7)
            const int tpos = ed ? (TX-1-t) : t;
            #pragma unroll
            for (int reg = 0; reg < 4; reg++){
                const int m = qL*4 + reg;
                const float ii = sigm(acc[0][reg]), ff = sigm(acc[1][reg]);
                const float gg = tanh_(acc[2][reg]), oo = sigm(acc[3][reg]);
                cst[reg] = ff*cst[reg] + ii*gg;
                const float hh = oo * tanh_(cst[reg]);
                const u16 hhi = f2bf(hh);
                const u16 hlo = f2bf(hh - bf2f_u16(hhi));
                sm.u.e.h[wb][ed][0][m][ub+mL] = hhi;
                sm.u.e.h[wb][ed][1][m][ub+mL] = hlo;
                sm.a[m][tpos][ed*32 + ub + mL] = hhi;
            }
        }
        #pragma unroll
        for (int reg = 0; reg < 4; reg++) cst[reg] = __shfl_xor(cst[reg], 32);  // c -> qL>=2 lanes
        __syncthreads();
        {   // h-MFMA step t+1: A rows 8-15 = h_t, rows 0-7 = 0
            const short8 Ahh = *(const short8*)((mL >= 8) ? &sm.u.e.h[wb][ed][0][mL-8][k0q] : &sm.u.e.zr[k0q]);
            const short8 Ahl = *(const short8*)((mL >= 8) ? &sm.u.e.h[wb][ed][1][mL-8][k0q] : &sm.u.e.zr[k0q]);
            #pragma unroll
            for (int gt = 0; gt < 4; gt++){
                acc[gt] = mfma16(Ahh, Bhh[gt], acc[gt]);
                acc[gt] = mfma16(Ahl, Bhh[gt], acc[gt]);
            }
        }
        if (qL >= 2){                                    // cell update step t+1 (rows 8-15)
            const int tpos = ed ? (TX-2-t) : (t+1);
            #pragma unroll
            for (int reg = 0; reg < 4; reg++){
                const int m = (qL-2)*4 + reg;
                const float ii = sigm(acc[0][reg]), ff = sigm(acc[1][reg]);
                const float gg = tanh_(acc[2][reg]), oo = sigm(acc[3][reg]);
                cst[reg] = ff*cst[reg] + ii*gg;
                const float hh = oo * tanh_(cst[reg]);
                const u16 hhi = f2bf(hh);
                const u16 hlo = f2bf(hh - bf2f_u16(hhi));
                sm.u.e.h[rb][ed][0][m][ub+mL] = hhi;
                sm.u.e.h[rb][ed][1][m][ub+mL] = hlo;
                sm.a[m][tpos][ed*32 + ub + mL] = hhi;
            }
        }
        #pragma unroll
        for (int reg = 0; reg < 4; reg++) cst[reg] = __shfl_xor(cst[reg], 32);  // c -> qL<2 lanes
        __syncthreads();
    };

    for (int tp = 0; tp < TX; tp += 2) epair(tp);

    // ===================== decoder setup =====================
    {   // zero sh, sl, ctxh, ctxl, zr2 (contiguous block)
        u32* z = (u32*)sm.u.d.sh;
        for (int i = tid; i < (4*BT*72 + 72)/2; i += 256) z[i] = 0u;
    }
    if (tid < 10) sm.u.d.w2b[tid] = W2[tid];
    if (tid == 0) sm.u.d.b2s = b2[0];

    // B-frags for aW1 = b1 + a @ W1[:, :64].T  (hi/lo split of W1 for fp32-class accuracy)
    short8 W1aB[2][2];
    #pragma unroll
    for (int kt = 0; kt < 2; kt++){
        short8 hv8, lv8;
        #pragma unroll
        for (int j = 0; j < 8; j++){
            const float v = (mL < 10) ? W1[mL*128 + kt*32 + k0q + j] : 0.f;
            const u16 hb = f2bf(v);
            hv8[j] = (short)hb;
            lv8[j] = (short)f2bf(v - bf2f_u16(hb));
        }
        W1aB[kt][0] = hv8; W1aB[kt][1] = lv8;
    }
    const float b1v = (mL < 10) ? b1[mL] : 0.f;

    // aW1 via MFMA: M=240 rows (r = b*30 + t), N=10, K=64; a rows contiguous at stride 64 u16
    for (int tile = wv; tile < 15; tile += 4){
        f4 accA = (f4){b1v, b1v, b1v, b1v};
        const u16* abase = &sm.a[0][0][0] + (tile*16 + mL)*64;
        #pragma unroll
        for (int kt = 0; kt < 2; kt++){
            const short8 av = *(const short8*)(abase + kt*32 + k0q);
            accA = mfma16(av, W1aB[kt][0], accA);
            accA = mfma16(av, W1aB[kt][1], accA);
        }
        if (mL < 10){
            #pragma unroll
            for (int reg = 0; reg < 4; reg++){
                const int r = tile*16 + qL*4 + reg;      // r < 240 always (15*16 = 240)
                (&sm.u.d.aW1[0][0][0])[r*10 + mL] = accA[reg];
            }
        }
    }

    const int uw = wv * 16;                              // decoder unit base (NS=64 over 4 waves)
    short8 Bip[4][2], Bhp[4][2]; float pb4[4];
    #pragma unroll
    for (int gt = 0; gt < 4; gt++){
        const int n = gt*64 + uw + mL;                   // post-cell gate row (chunks of 64)
        #pragma unroll
        for (int kt = 0; kt < 2; kt++){
            const float* p = Wihp + n*64 + kt*32 + k0q;
            const float* q = Whhp + n*64 + kt*32 + k0q;
            short8 s1v, s2v;
            #pragma unroll
            for (int j = 0; j < 8; j++){ s1v[j] = (short)f2bf(p[j]); s2v[j] = (short)f2bf(q[j]); }
            Bip[gt][kt] = s1v; Bhp[gt][kt] = s2v;
        }
        pb4[gt] = bp[n];
    }
    short8 Bo2[2];
    {
        const int n = uw + mL;
        #pragma unroll
        for (int kt = 0; kt < 2; kt++){
            const float* p = Wo + n*64 + kt*32 + k0q;
            short8 s;
            #pragma unroll
            for (int j = 0; j < 8; j++) s[j] = (short)f2bf(p[j]);
            Bo2[kt] = s;
        }
    }
    short8 W1sB[2];                                      // B-frag of W1[:,64:128], n=mL (rows>=10 zero)
    #pragma unroll
    for (int kt = 0; kt < 2; kt++){
        short8 s;
        #pragma unroll
        for (int j = 0; j < 8; j++){
            const float v = (mL < 10) ? W1[mL*128 + 64 + kt*32 + k0q + j] : 0.f;
            s[j] = (short)f2bf(v);
        }
        W1sB[kt] = s;
    }
    const float boL = bo[uw + mL];
    float cs2[4] = {0.f,0.f,0.f,0.f};
    __syncthreads();

    // ===================== decoder loop =====================
    for (int ty = 0; ty < TY; ty++){
        {   // sW1 = s @ W1[:,64:].T via MFMA (4 MFMAs, all waves redundantly)
            f4 accW = (f4){0.f,0.f,0.f,0.f};
            #pragma unroll
            for (int kt = 0; kt < 2; kt++){
                const int ko = kt*32 + k0q;
                const short8 shh = *(const short8*)((mL < 8) ? &sm.u.d.sh[mL][ko] : &sm.u.d.zr2[ko]);
                const short8 sll = *(const short8*)((mL < 8) ? &sm.u.d.sl[mL][ko] : &sm.u.d.zr2[ko]);
                accW = mfma16(shh, W1sB[kt], accW);
                accW = mfma16(sll, W1sB[kt], accW);
            }
            if (qL < 2 && mL < 10 && wv == 0){
                #pragma unroll
                for (int reg = 0; reg < 4; reg++) sm.u.d.sW1[qL*4+reg][mL] = accW[reg];
            }
        }
        __syncthreads();
        if (tid < 240){                                  // en = relu(tanh(aW1+sW1) . w2 + b2)
            const int er = tid/30, et = tid - er*30;
            float env = sm.u.d.b2s;
            #pragma unroll
            for (int j = 0; j < 10; j++){
                const float z = sm.u.d.aW1[er][et][j] + sm.u.d.sW1[er][j];
                env += sm.u.d.w2b[j]*tanh_(z);
            }
            sm.u.d.en[er][et] = fmaxf(env, 0.f);
        }
        __syncthreads();
        {   // fused softmax+context: single exp pass, normalize at end
            const int cr = tid >> 5, cup = tid & 31;
            const float* enr = sm.u.d.en[cr];
            float mx = enr[0];
            #pragma unroll
            for (int t2 = 1; t2 < TX; t2++) mx = fmaxf(mx, enr[t2]);
            float ssum = 0.f, s0 = 0.f, s1 = 0.f;
            const u16* ap = &sm.a[cr][0][2*cup];
            #pragma unroll 5
            for (int t2 = 0; t2 < TX; t2++){
                const float e = __expf(enr[t2]-mx);
                const u32 pa = *(const u32*)(ap + t2*64);
                ssum += e;
                s0 += e*lo2f(pa); s1 += e*hi2f(pa);
            }
            const float inv = frcp(ssum);
            s0 *= inv; s1 *= inv;
            const u16 h0 = f2bf(s0), h1 = f2bf(s1);
            const u16 l0 = f2bf(s0 - bf2f_u16(h0)), l1 = f2bf(s1 - bf2f_u16(h1));
            *(u32*)&sm.u.d.ctxh[cr][2*cup] = (u32)h0 | ((u32)h1 << 16);
            *(u32*)&sm.u.d.ctxl[cr][2*cup] = (u32)l0 | ((u32)l1 << 16);
        }
        __syncthreads();
        // z2 = [ctx|s] @ Wp^T + bp   (in-register gates)
        f4 acc2[4];
        #pragma unroll
        for (int gt = 0; gt < 4; gt++) acc2[gt] = (f4){pb4[gt],pb4[gt],pb4[gt],pb4[gt]};
        #pragma unroll
        for (int kt = 0; kt < 2; kt++){
            const int ko = kt*32 + k0q;
            const bool v8 = (mL < 8);
            const short8 ch  = *(const short8*)(v8 ? &sm.u.d.ctxh[mL][ko] : &sm.u.d.zr2[ko]);
            const short8 cl  = *(const short8*)(v8 ? &sm.u.d.ctxl[mL][ko] : &sm.u.d.zr2[ko]);
            const short8 shh = *(const short8*)(v8 ? &sm.u.d.sh[mL][ko]   : &sm.u.d.zr2[ko]);
            const short8 sll = *(const short8*)(v8 ? &sm.u.d.sl[mL][ko]   : &sm.u.d.zr2[ko]);
            #pragma unroll
            for (int gt = 0; gt < 4; gt++){
                acc2[gt] = mfma16(ch,  Bip[gt][kt], acc2[gt]);
                acc2[gt] = mfma16(cl,  Bip[gt][kt], acc2[gt]);
                acc2[gt] = mfma16(shh, Bhp[gt][kt], acc2[gt]);
                acc2[gt] = mfma16(sll, Bhp[gt][kt], acc2[gt]);
            }
        }
        __syncthreads();                                 // frag reads done before s overwrite
        if (qL < 2){
            #pragma unroll
            for (int reg = 0; reg < 4; reg++){
                const int m = qL*4 + reg;
                const float ii = sigm(acc2[0][reg]), ff = sigm(acc2[1][reg]);
                const float gg = tanh_(acc2[2][reg]), oo = sigm(acc2[3][reg]);
                cs2[reg] = ff*cs2[reg] + ii*gg;
                const float sv = oo * tanh_(cs2[reg]);
                const u16 shi = f2bf(sv);
                const u16 slo = f2bf(sv - bf2f_u16(shi));
                sm.u.d.sh[m][uw+mL]  = shi;
                sm.u.d.sl[m][uw+mL]  = slo;
            }
        }
        __syncthreads();
        // out = s @ Wo^T + bo
        f4 acc3 = (f4){boL, boL, boL, boL};
        #pragma unroll
        for (int kt = 0; kt < 2; kt++){
            const int ko = kt*32 + k0q;
            const short8 shh = *(const short8*)((mL < 8) ? &sm.u.d.sh[mL][ko] : &sm.u.d.zr2[ko]);
            const short8 sll = *(const short8*)((mL < 8) ? &sm.u.d.sl[mL][ko] : &sm.u.d.zr2[ko]);
            acc3 = mfma16(shh, Bo2[kt], acc3);
            acc3 = mfma16(sll, Bo2[kt], acc3);
        }
        if (qL < 2){
            #pragma unroll
            for (int reg = 0; reg < 4; reg++){
                const int m = qL*4 + reg;
                out[(((long)(b0+m))*TY + ty)*64 + uw + mL] = acc3[reg];
            }
        }
    }
}

extern "C" void kernel_launch(void* const* d_in, const int* in_sizes, int n_in,
                              void* d_out, int out_size, void* d_ws, size_t ws_size,
                              hipStream_t stream) {
    const float* X    = (const float*)d_in[0];
    const float* Wihf = (const float*)d_in[1];
    const float* Whhf = (const float*)d_in[2];
    const float* bfv  = (const float*)d_in[3];
    const float* Wihr = (const float*)d_in[4];
    const float* Whhr = (const float*)d_in[5];
    const float* brv  = (const float*)d_in[6];
    const float* W1   = (const float*)d_in[7];
    const float* b1   = (const float*)d_in[8];
    const float* W2   = (const float*)d_in[9];
    const float* b2   = (const float*)d_in[10];
    const float* Wihp = (const float*)d_in[11];
    const float* Whhp = (const float*)d_in[12];
    const float* bp   = (const float*)d_in[13];
    const float* Wo   = (const float*)d_in[14];
    const float* bo   = (const float*)d_in[15];
    float* out = (float*)d_out;

    const int B = in_sizes[0] / (TX * 128);
    dim3 grid(B / BT), block(256);
    hipLaunchKernelGGL(fused_kernel, grid, block, 0, stream,
                       X, Wihf, Whhf, bfv, Wihr, Whhr, brv,
                       W1, b1, W2, b2, Wihp, Whhp, bp, Wo, bo, out);
}

// Round 5
// 614.645 us; speedup vs baseline: 1.2996x; 1.2996x over previous
//
#include <hip/hip_runtime.h>

typedef unsigned short u16;
typedef unsigned int   u32;
typedef __attribute__((ext_vector_type(8))) short short8;
typedef __attribute__((ext_vector_type(4))) float f4;

#define BT 16
#define TX 30
#define TY 10

__device__ __forceinline__ float bf2f_u16(u16 h){ u32 i=((u32)h)<<16; float f; __builtin_memcpy(&f,&i,4); return f; }
__device__ __forceinline__ float lo2f(u32 p){ u32 i=p<<16; float f; __builtin_memcpy(&f,&i,4); return f; }
__device__ __forceinline__ float hi2f(u32 p){ u32 i=p&0xffff0000u; float f; __builtin_memcpy(&f,&i,4); return f; }
__device__ __forceinline__ u16 f2bf(float f){ u32 x; __builtin_memcpy(&x,&f,4); u32 r=(x+0x7fffu+((x>>16)&1u))>>16; return (u16)r; }

#if __has_builtin(__builtin_amdgcn_rcpf)
__device__ __forceinline__ float frcp(float x){ return __builtin_amdgcn_rcpf(x); }
#else
__device__ __forceinline__ float frcp(float x){ return 1.0f/x; }
#endif
__device__ __forceinline__ float sigm(float x){ return frcp(1.0f+__expf(-x)); }
__device__ __forceinline__ float tanh_(float x){ x=fminf(fmaxf(x,-15.0f),15.0f); float e=__expf(2.0f*x); return 1.0f - 2.0f*frcp(e+1.0f); }

__device__ __forceinline__ f4 mfma16(short8 a, short8 b, f4 c){
    return __builtin_amdgcn_mfma_f32_16x16x32_bf16(a, b, c, 0, 0, 0);
}

union S8u { short8 s; u32 u[4]; };

// pack hi-halves of two fp32 into one u32 (truncated bf16 pair), residual -> lo pair
__device__ __forceinline__ void cvt_pair(float a0, float a1, u32& hp, u32& lp){
    u32 u0, u1; __builtin_memcpy(&u0,&a0,4); __builtin_memcpy(&u1,&a1,4);
    hp = __builtin_amdgcn_perm(u1, u0, 0x07060302u);
    float r0 = a0 - hi2f(u0);
    float r1 = a1 - hi2f(u1);
    u32 v0, v1; __builtin_memcpy(&v0,&r0,4); __builtin_memcpy(&v1,&r1,4);
    lp = __builtin_amdgcn_perm(v1, v0, 0x07060302u);
}

// All [*][64]-u16 LDS tiles use an involutive 16B-block XOR swizzle keyed by a
// row value: phys_blk = blk ^ (key&7). Applied identically on write and read.
struct SDec {
    u16 sh[BT][64], sl[BT][64];     // s hi/lo, key = batch&7
    u16 ctxh[BT][64], ctxl[BT][64]; // context hi/lo, key = batch&7
    float en[BT*TX];                // 480 f32, flat r = b*30 + t
};
struct SEnc {
    u16 h[2][2][2][BT][40];         // [parity][dir][hi/lo][batch][k], K=32 pad 40
};
union UU { SEnc e; SDec d; };
struct Smem {
    u16 a[BT*TX][64];               // encoder out bf16, row r=b*30+t, key=(b+t)&7
    UU u;
};
static_assert(sizeof(SEnc) == 10240, "enc");
static_assert(sizeof(SDec) == 10112, "dec");
static_assert(sizeof(Smem) == 71680, "LDS 70KB -> 2 blocks/CU");

__global__ __launch_bounds__(256, 2) void fused_kernel(
    const float* __restrict__ X,
    const float* __restrict__ Wihf, const float* __restrict__ Whhf, const float* __restrict__ bfv,
    const float* __restrict__ Wihr, const float* __restrict__ Whhr, const float* __restrict__ brv,
    const float* __restrict__ W1, const float* __restrict__ b1, const float* __restrict__ W2, const float* __restrict__ b2,
    const float* __restrict__ Wihp, const float* __restrict__ Whhp, const float* __restrict__ bp,
    const float* __restrict__ Wo, const float* __restrict__ bo,
    float* __restrict__ out)
{
    __shared__ __align__(16) Smem sm;
    const int tid = threadIdx.x;
    const int b0  = blockIdx.x * BT;

    const int lane = tid & 63;
    const int wv   = tid >> 6;     // wave 0..3
    const int mL   = lane & 15;    // frag non-K index
    const int qL   = lane >> 4;    // quad
    const int k0q  = qL * 8;
    const int ed   = wv >> 1;      // encoder dir
    const int ub   = (wv & 1) * 16;// encoder unit base within NA=32

    {   // zero encoder h buffers (10240 B)
        u32* p = (u32*)&sm.u.e;
        for (int i = tid; i < 2560; i += 256) p[i] = 0u;
    }
    __syncthreads();

    // ===================== encoder =====================
    const float* Wih = ed ? Wihr : Wihf;
    const float* Whh = ed ? Whhr : Whhf;
    const float* bv  = ed ? brv  : bfv;

    short8 Bih[4][4]; short8 Bhh[4]; float bias4[4];
    #pragma unroll
    for (int gt = 0; gt < 4; gt++){
        const int n = gt*32 + ub + mL;                  // gate row (i,f,g,o chunks of 32)
        #pragma unroll
        for (int kt = 0; kt < 4; kt++){
            const float* p = Wih + n*128 + kt*32 + k0q;
            short8 s;
            #pragma unroll
            for (int j = 0; j < 8; j++) s[j] = (short)f2bf(p[j]);
            Bih[gt][kt] = s;
        }
        {
            const float* p = Whh + n*32 + k0q;
            short8 s;
            #pragma unroll
            for (int j = 0; j < 8; j++) s[j] = (short)f2bf(p[j]);
            Bhh[gt] = s;
        }
        bias4[gt] = bv[n];
    }

    const float* xrow = X + ((long)(b0 + mL)) * TX * 128;   // A row = batch mL
    float cst[4] = {0.f,0.f,0.f,0.f};                        // c-state, fully lane-resident

    // single step t: all 16 batches in one fragment (full lanes in cell update)
    auto estep = [&](int t, f4* cur, f4* nxt){
        if (t + 1 < TX){                                 // prefetch next step
            const int ts = ed ? (TX-2-t) : (t+1);
            const float* p = xrow + ts*128 + k0q;
            #pragma unroll
            for (int kt = 0; kt < 4; kt++){
                nxt[2*kt]   = *(const f4*)(p + kt*32);
                nxt[2*kt+1] = *(const f4*)(p + kt*32 + 4);
            }
        }
        const int rb = (t+1) & 1, wb = t & 1;

        f4 acc[4];
        #pragma unroll
        for (int gt = 0; gt < 4; gt++) acc[gt] = (f4){bias4[gt],bias4[gt],bias4[gt],bias4[gt]};

        #pragma unroll
        for (int kt = 0; kt < 4; kt++){                  // x-GEMM
            S8u xh, xl;
            cvt_pair(cur[2*kt][0],   cur[2*kt][1],   xh.u[0], xl.u[0]);
            cvt_pair(cur[2*kt][2],   cur[2*kt][3],   xh.u[1], xl.u[1]);
            cvt_pair(cur[2*kt+1][0], cur[2*kt+1][1], xh.u[2], xl.u[2]);
            cvt_pair(cur[2*kt+1][2], cur[2*kt+1][3], xh.u[3], xl.u[3]);
            #pragma unroll
            for (int gt = 0; gt < 4; gt++){
                acc[gt] = mfma16(xh.s, Bih[gt][kt], acc[gt]);
                acc[gt] = mfma16(xl.s, Bih[gt][kt], acc[gt]);
            }
        }
        {   // h-MFMA: A = h_{t-1}, all 16 rows real
            const short8 Ahh = *(const short8*)&sm.u.e.h[rb][ed][0][mL][k0q];
            const short8 Ahl = *(const short8*)&sm.u.e.h[rb][ed][1][mL][k0q];
            #pragma unroll
            for (int gt = 0; gt < 4; gt++){
                acc[gt] = mfma16(Ahh, Bhh[gt], acc[gt]);
                acc[gt] = mfma16(Ahl, Bhh[gt], acc[gt]);
            }
        }
        const int tpos = ed ? (TX-1-t) : t;
        const int u = ed*32 + ub + mL;
        #pragma unroll
        for (int reg = 0; reg < 4; reg++){               // cell update: ALL 64 lanes
            const int m = qL*4 + reg;
            const float ii = sigm(acc[0][reg]), ff = sigm(acc[1][reg]);
            const float gg = tanh_(acc[2][reg]), oo = sigm(acc[3][reg]);
            cst[reg] = ff*cst[reg] + ii*gg;
            const float hh = oo * tanh_(cst[reg]);
            const u16 hhi = f2bf(hh);
            const u16 hlo = f2bf(hh - bf2f_u16(hhi));
            sm.u.e.h[wb][ed][0][m][ub+mL] = hhi;
            sm.u.e.h[wb][ed][1][m][ub+mL] = hlo;
            const int r = m*TX + tpos;
            sm.a[r][(((u>>3) ^ ((m+tpos)&7))<<3) | (u&7)] = hhi;
        }
        __syncthreads();
    };

    f4 rawA[8], rawB[8];
    {   // initial load: step 0
        const int ts0 = ed ? (TX-1) : 0;
        const float* p = xrow + ts0*128 + k0q;
        #pragma unroll
        for (int kt = 0; kt < 4; kt++){
            rawA[2*kt]   = *(const f4*)(p + kt*32);
            rawA[2*kt+1] = *(const f4*)(p + kt*32 + 4);
        }
    }
    for (int t = 0; t < TX; t += 2){ estep(t, rawA, rawB); estep(t+1, rawB, rawA); }

    // ===================== decoder setup =====================
    {   // zero sh, sl (contiguous 4096 B)
        u32* z = (u32*)sm.u.d.sh;
        for (int i = tid; i < 1024; i += 256) z[i] = 0u;
    }
    // e = tanh(a @ W1[:,:64].T + s @ W1[:,64:].T + b1); en = relu(e . w2 + b2)
    short8 W1aB[2][2];                                   // W1[:, :64] hi/lo B-frags
    #pragma unroll
    for (int kt = 0; kt < 2; kt++){
        short8 hv8, lv8;
        #pragma unroll
        for (int j = 0; j < 8; j++){
            const float v = (mL < 10) ? W1[mL*128 + kt*32 + k0q + j] : 0.f;
            const u16 hb = f2bf(v);
            hv8[j] = (short)hb;
            lv8[j] = (short)f2bf(v - bf2f_u16(hb));
        }
        W1aB[kt][0] = hv8; W1aB[kt][1] = lv8;
    }
    short8 W1sB[2];                                      // W1[:, 64:128] hi B-frag
    #pragma unroll
    for (int kt = 0; kt < 2; kt++){
        short8 s;
        #pragma unroll
        for (int j = 0; j < 8; j++){
            const float v = (mL < 10) ? W1[mL*128 + 64 + kt*32 + k0q + j] : 0.f;
            s[j] = (short)f2bf(v);
        }
        W1sB[kt] = s;
    }
    const float b1v = (mL < 10) ? b1[mL] : 0.f;
    const float w2v = (mL < 10) ? W2[mL] : 0.f;
    const float b2s = b2[0];

    const int uw = wv * 16;                              // decoder unit base (NS=64 over 4 waves)
    short8 Bip[4][2], Bhp[4][2]; float pb4[4];
    #pragma unroll
    for (int gt = 0; gt < 4; gt++){
        const int n = gt*64 + uw + mL;
        #pragma unroll
        for (int kt = 0; kt < 2; kt++){
            const float* p = Wihp + n*64 + kt*32 + k0q;
            const float* q = Whhp + n*64 + kt*32 + k0q;
            short8 s1v, s2v;
            #pragma unroll
            for (int j = 0; j < 8; j++){ s1v[j] = (short)f2bf(p[j]); s2v[j] = (short)f2bf(q[j]); }
            Bip[gt][kt] = s1v; Bhp[gt][kt] = s2v;
        }
        pb4[gt] = bp[n];
    }
    short8 Bo2[2];
    {
        const int n = uw + mL;
        #pragma unroll
        for (int kt = 0; kt < 2; kt++){
            const float* p = Wo + n*64 + kt*32 + k0q;
            short8 s;
            #pragma unroll
            for (int j = 0; j < 8; j++) s[j] = (short)f2bf(p[j]);
            Bo2[kt] = s;
        }
    }
    const float boL = bo[uw + mL];
    float cs2[4] = {0.f,0.f,0.f,0.f};
    const u16* aflat  = &sm.a[0][0];
    u16* shf = &sm.u.d.sh[0][0];
    u16* slf = &sm.u.d.sl[0][0];
    u16* chf = &sm.u.d.ctxh[0][0];
    u16* clf = &sm.u.d.ctxl[0][0];
    __syncthreads();

    // ===================== decoder loop (4 barriers/ty) =====================
    for (int ty = 0; ty < TY; ty++){
        // phase A: en for all 480 (b,t) rows via fused MFMA (a·W1a + s·W1s + b1)
        for (int tt = wv; tt < TX; tt += 4){
            const int r = tt*16 + mL;
            const int b = (r * 34953) >> 20;             // r/30 for r<480
            const int tp2 = r - b*30;
            f4 accE = (f4){b1v, b1v, b1v, b1v};
            const u16* ab = aflat + r*64;
            const int keyA = (b + tp2) & 7;
            #pragma unroll
            for (int kt = 0; kt < 2; kt++){
                const short8 av = *(const short8*)(ab + (((kt*4+qL)^keyA)<<3));
                accE = mfma16(av, W1aB[kt][0], accE);
                accE = mfma16(av, W1aB[kt][1], accE);
            }
            const int keyS = b & 7;
            #pragma unroll
            for (int kt = 0; kt < 2; kt++){
                const int off = b*64 + (((kt*4+qL)^keyS)<<3);
                const short8 shh = *(const short8*)(shf + off);
                const short8 sll = *(const short8*)(slf + off);
                accE = mfma16(shh, W1sB[kt], accE);
                accE = mfma16(sll, W1sB[kt], accE);
            }
            float er[4];
            #pragma unroll
            for (int reg = 0; reg < 4; reg++) er[reg] = w2v * tanh_(accE[reg]);
            #pragma unroll
            for (int d = 1; d < 16; d <<= 1){
                #pragma unroll
                for (int reg = 0; reg < 4; reg++) er[reg] += __shfl_xor(er[reg], d);
            }
            if (mL == 0){
                f4 ev;
                #pragma unroll
                for (int reg = 0; reg < 4; reg++) ev[reg] = fmaxf(er[reg] + b2s, 0.f);
                *(f4*)&sm.u.d.en[tt*16 + qL*4] = ev;
            }
        }
        __syncthreads();
        {   // fused softmax+context: 16 rows x 16 lanes, 4 units/lane
            const int cr = tid >> 4, cup = tid & 15;
            const float* enr = &sm.u.d.en[cr*30];
            float mx = enr[0];
            #pragma unroll
            for (int t2 = 1; t2 < TX; t2++) mx = fmaxf(mx, enr[t2]);
            float ssum = 0.f, s0 = 0.f, s1 = 0.f, s2v_ = 0.f, s3 = 0.f;
            #pragma unroll 5
            for (int t2 = 0; t2 < TX; t2++){
                const float e = __expf(enr[t2]-mx);
                const u16* ap = aflat + (cr*30+t2)*64
                              + ((((cup>>1) ^ ((cr+t2)&7))<<3) | ((cup&1)<<2));
                const u32 pa0 = *(const u32*)ap;
                const u32 pa1 = *(const u32*)(ap + 2);
                ssum += e;
                s0 += e*lo2f(pa0); s1 += e*hi2f(pa0);
                s2v_ += e*lo2f(pa1); s3 += e*hi2f(pa1);
            }
            const float inv = frcp(ssum);
            s0 *= inv; s1 *= inv; s2v_ *= inv; s3 *= inv;
            const u16 h0 = f2bf(s0), h1 = f2bf(s1), h2 = f2bf(s2v_), h3 = f2bf(s3);
            const u16 l0 = f2bf(s0 - bf2f_u16(h0)), l1 = f2bf(s1 - bf2f_u16(h1));
            const u16 l2 = f2bf(s2v_ - bf2f_u16(h2)), l3 = f2bf(s3 - bf2f_u16(h3));
            const int off = cr*64 + ((((cup>>1) ^ (cr&7))<<3) | ((cup&1)<<2));
            *(u32*)(chf + off)     = (u32)h0 | ((u32)h1 << 16);
            *(u32*)(chf + off + 2) = (u32)h2 | ((u32)h3 << 16);
            *(u32*)(clf + off)     = (u32)l0 | ((u32)l1 << 16);
            *(u32*)(clf + off + 2) = (u32)l2 | ((u32)l3 << 16);
        }
        __syncthreads();
        // z2 = [ctx|s] @ Wp^T + bp : all 16 A-rows real
        f4 acc2[4];
        #pragma unroll
        for (int gt = 0; gt < 4; gt++) acc2[gt] = (f4){pb4[gt],pb4[gt],pb4[gt],pb4[gt]};
        #pragma unroll
        for (int kt = 0; kt < 2; kt++){
            const int off = mL*64 + (((kt*4+qL) ^ (mL&7))<<3);
            const short8 ch  = *(const short8*)(chf + off);
            const short8 cl  = *(const short8*)(clf + off);
            const short8 shh = *(const short8*)(shf + off);
            const short8 sll = *(const short8*)(slf + off);
            #pragma unroll
            for (int gt = 0; gt < 4; gt++){
                acc2[gt] = mfma16(ch,  Bip[gt][kt], acc2[gt]);
                acc2[gt] = mfma16(cl,  Bip[gt][kt], acc2[gt]);
                acc2[gt] = mfma16(shh, Bhp[gt][kt], acc2[gt]);
                acc2[gt] = mfma16(sll, Bhp[gt][kt], acc2[gt]);
            }
        }
        __syncthreads();                                 // frag reads done before s overwrite
        #pragma unroll
        for (int reg = 0; reg < 4; reg++){               // cell update: ALL 64 lanes
            const int m = qL*4 + reg;
            const float ii = sigm(acc2[0][reg]), ff = sigm(acc2[1][reg]);
            const float gg = tanh_(acc2[2][reg]), oo = sigm(acc2[3][reg]);
            cs2[reg] = ff*cs2[reg] + ii*gg;
            const float sv = oo * tanh_(cs2[reg]);
            const u16 shi = f2bf(sv);
            const u16 slo = f2bf(sv - bf2f_u16(shi));
            const int u2 = uw + mL;
            const int idx = m*64 + ((((u2>>3) ^ (m&7))<<3) | (u2&7));
            shf[idx] = shi;
            slf[idx] = slo;
        }
        __syncthreads();
        // out = s @ Wo^T + bo  (reads sh/sl; next phaseA also only reads -> no barrier)
        f4 acc3 = (f4){boL, boL, boL, boL};
        #pragma unroll
        for (int kt = 0; kt < 2; kt++){
            const int off = mL*64 + (((kt*4+qL) ^ (mL&7))<<3);
            const short8 shh = *(const short8*)(shf + off);
            const short8 sll = *(const short8*)(slf + off);
            acc3 = mfma16(shh, Bo2[kt], acc3);
            acc3 = mfma16(sll, Bo2[kt], acc3);
        }
        #pragma unroll
        for (int reg = 0; reg < 4; reg++){
            const int m = qL*4 + reg;
            out[(((long)(b0+m))*TY + ty)*64 + uw + mL] = acc3[reg];
        }
    }
}

extern "C" void kernel_launch(void* const* d_in, const int* in_sizes, int n_in,
                              void* d_out, int out_size, void* d_ws, size_t ws_size,
                              hipStream_t stream) {
    const float* X    = (const float*)d_in[0];
    const float* Wihf = (const float*)d_in[1];
    const float* Whhf = (const float*)d_in[2];
    const float* bfv  = (const float*)d_in[3];
    const float* Wihr = (const float*)d_in[4];
    const float* Whhr = (const float*)d_in[5];
    const float* brv  = (const float*)d_in[6];
    const float* W1   = (const float*)d_in[7];
    const float* b1   = (const float*)d_in[8];
    const float* W2   = (const float*)d_in[9];
    const float* b2   = (const float*)d_in[10];
    const float* Wihp = (const float*)d_in[11];
    const float* Whhp = (const float*)d_in[12];
    const float* bp   = (const float*)d_in[13];
    const float* Wo   = (const float*)d_in[14];
    const float* bo   = (const float*)d_in[15];
    float* out = (float*)d_out;

    const int B = in_sizes[0] / (TX * 128);
    dim3 grid(B / BT), block(256);
    hipLaunchKernelGGL(fused_kernel, grid, block, 0, stream,
                       X, Wihf, Whhf, bfv, Wihr, Whhr, brv,
                       W1, b1, W2, b2, Wihp, Whhp, bp, Wo, bo, out);
}